// Round 2
// baseline (1004.888 us; speedup 1.0000x reference)
//
#include <hip/hip_runtime.h>
#include <hip/hip_bf16.h>
#include <stdint.h>

typedef uint16_t u16;
typedef uint32_t u32;
typedef uint64_t u64;
typedef short bf16x8 __attribute__((ext_vector_type(8)));   // 8 bf16 in 4 VGPRs
typedef float f32x4 __attribute__((ext_vector_type(4)));
typedef u32 u32x4 __attribute__((ext_vector_type(4)));

#define E_N 131072
#define T_N 1048576

__device__ __forceinline__ float bf2f(u32 u) { return __builtin_bit_cast(float, u << 16); }
__device__ __forceinline__ u16 f2bf(float f) {
  u32 u = __builtin_bit_cast(u32, f);
  return (u16)((u + 0x7fffu + ((u >> 16) & 1u)) >> 16);   // RNE
}
__device__ __forceinline__ float silu_f(float x) { return x / (1.0f + __expf(-x)); }
__device__ __forceinline__ f32x4 mfma16(bf16x8 a, bf16x8 b, f32x4 c) {
  return __builtin_amdgcn_mfma_f32_16x16x32_bf16(a, b, c, 0, 0, 0);
}
// async global->LDS, 16B per lane. LDS dest is wave-uniform base + lane*16;
// swizzle is applied on the GLOBAL source address (rule #21).
__device__ __forceinline__ void gld_lds16(const void* g, void* l) {
  __builtin_amdgcn_global_load_lds((const __attribute__((address_space(1))) u32*)g,
                                   (__attribute__((address_space(3))) u32*)l, 16, 0, 0);
}

// ---------------------------------------------------------------------------
// T0: convert+transpose all f32 weight matrices into ws as [n][k] row-major bf16.
//  region 0: W2T[256][128]   (n<128: W_ji, n>=128: W_kj)       32768 elts
//  region 1: WbilT[8][128][128]                                131072 elts
//  region 2: {r1w1,r1w2,r2w1,r2w2,Wout}T each [128][128]       81920 elts
__global__ __launch_bounds__(256) void k_transpose(
    const float* __restrict__ Wji, const float* __restrict__ Wkj, const float* __restrict__ Wbil,
    const float* __restrict__ w11, const float* __restrict__ w12,
    const float* __restrict__ w21, const float* __restrict__ w22, const float* __restrict__ wout,
    u16* __restrict__ dst) {
  u32 idx = blockIdx.x * 256 + threadIdx.x;
  if (idx < 32768) {
    u32 n = idx >> 7, h = idx & 127;
    dst[idx] = f2bf((n < 128) ? Wji[h * 128 + n] : Wkj[h * 128 + (n - 128)]);
  } else if (idx < 32768 + 131072) {
    u32 q = idx - 32768;
    u32 b = q >> 14, n = (q >> 7) & 127, h = q & 127;
    dst[idx] = f2bf(Wbil[h * 1024 + b * 128 + n]);
  } else if (idx < 245760) {
    u32 q = idx - 163840;
    u32 r = q >> 14, n = (q >> 7) & 127, h = q & 127;
    const float* src = (r == 0) ? w11 : (r == 1) ? w12 : (r == 2) ? w21 : (r == 3) ? w22 : wout;
    dst[idx] = f2bf(src[h * 128 + n]);
  }
}

// ---------------------------------------------------------------------------
// S2: per-edge pre-GEMM.  [128 rows] x W2T[256][128].
//  cols   0..127 : aggr[row][col] = silu(m@W_ji + b_ji)   (f32, seeds segment sum)
//  cols 128..255 : ek[row][c2]    = silu(m@W_kj + b_kj) * (rbf@W_rbf)   (bf16)
__global__ __launch_bounds__(512) void k_pre(
    const float* __restrict__ m, const float* __restrict__ rbf, const float* __restrict__ Wrbf,
    const float* __restrict__ bkj, const float* __restrict__ bji,
    const char* __restrict__ W2T, float* __restrict__ aggr, u16* __restrict__ ek) {
  extern __shared__ char lds[];
  char* ldsA = lds;                              // 32768: m tile [128][128] bf16 (swz)
  char* ldsB = lds + 32768;                      // 65536: W2T [256][128] bf16 (swz)
  float* ldsRbf = (float*)(lds + 98304);         // [128][6]
  float* ldsWr = (float*)(lds + 101376);         // [6][128]
  const u32 tid = threadIdx.x, lane = tid & 63;
  const u32 r0 = blockIdx.x << 7;

  // stage m (f32) -> bf16 swizzled LDS, reg-staged
#pragma unroll
  for (int it = 0; it < 8; ++it) {
    u32 q = tid + it * 512;          // [0,4096): 128 rows x 32 groups of 4 elems
    u32 row = q >> 5, c4 = q & 31;
    f32x4 v = *(const f32x4*)(m + (size_t)(r0 + row) * 128 + c4 * 4);
    u32 c = c4 >> 1, half = c4 & 1;
    u32 w0 = (u32)f2bf(v[0]) | ((u32)f2bf(v[1]) << 16);
    u32 w1 = (u32)f2bf(v[2]) | ((u32)f2bf(v[3]) << 16);
    u32 ofs = (row << 8) + ((c ^ (row & 7)) << 4) + half * 8;
    *(u64*)(ldsA + ofs) = (u64)w0 | ((u64)w1 << 32);
  }
#pragma unroll
  for (int it = 0; it < 8; ++it) {   // W2T bf16 via async copy
    u32 q = tid + it * 512, n = q >> 4, c = q & 15;
    gld_lds16(W2T + n * 256 + ((c ^ (n & 7)) << 4), ldsB + q * 16);
  }
  for (u32 i = tid; i < 768; i += 512) ldsRbf[i] = rbf[(size_t)r0 * 6 + i];
  for (u32 i = tid; i < 768; i += 512) ldsWr[i] = Wrbf[i];
  __syncthreads();

  const u32 wid = tid >> 6, wm = wid >> 2, wn = wid & 3;
  const u32 rb = wm << 6, cb = wn << 6;
  f32x4 acc[4][4] = {};
  bf16x8 Bf[4][4];
#pragma unroll
  for (int ni = 0; ni < 4; ++ni) {
    u32 n = cb + ni * 16 + (lane & 15);
#pragma unroll
    for (int ks = 0; ks < 4; ++ks)
      Bf[ni][ks] = *(const bf16x8*)(ldsB + (n << 8) + ((((u32)(ks * 4) + (lane >> 4)) ^ (n & 7)) << 4));
  }
#pragma unroll
  for (int mi = 0; mi < 4; ++mi) {
    u32 row = rb + mi * 16 + (lane & 15);
    bf16x8 Af[4];
#pragma unroll
    for (int ks = 0; ks < 4; ++ks)
      Af[ks] = *(const bf16x8*)(ldsA + (row << 8) + ((((u32)(ks * 4) + (lane >> 4)) ^ (row & 7)) << 4));
#pragma unroll
    for (int ni = 0; ni < 4; ++ni)
#pragma unroll
      for (int ks = 0; ks < 4; ++ks) acc[mi][ni] = mfma16(Af[ks], Bf[ni][ks], acc[mi][ni]);
  }
  // epilogue
#pragma unroll
  for (int mi = 0; mi < 4; ++mi) {
    u32 rloc = rb + mi * 16 + ((lane >> 4) << 2);
#pragma unroll
    for (int j = 0; j < 4; ++j) {
      u32 rl = rloc + j;
      size_t grow = r0 + rl;
#pragma unroll
      for (int ni = 0; ni < 4; ++ni) {
        u32 col = cb + ni * 16 + (lane & 15);
        float v = acc[mi][ni][j];
        if (col < 128) {
          aggr[grow * 128 + col] = silu_f(v + bji[col]);
        } else {
          u32 c2 = col - 128;
          float rw = 0.f;
#pragma unroll
          for (int q = 0; q < 6; ++q) rw += ldsRbf[rl * 6 + q] * ldsWr[q * 128 + c2];
          ek[grow * 128 + c2] = f2bf(silu_f(v + bkj[c2]) * rw);
        }
      }
    }
  }
}

// ---------------------------------------------------------------------------
// S3: sbf_proj = sbf @ W_sbf  -> sp[T][8] f32.  256 rows per 256-thread block.
__global__ __launch_bounds__(256) void k_sbf(
    const float* __restrict__ sbf, const float* __restrict__ Wsbf, float* __restrict__ sp) {
  extern __shared__ char lds[];
  float* s_lds = (float*)lds;              // 256*42 f32 = 43008 B
  float* w_lds = (float*)(lds + 43008);    // [42][8]
  const u32 tid = threadIdx.x;
  const u32 t0 = blockIdx.x << 8;
  for (u32 i = tid; i < 256 * 42; i += 256) s_lds[i] = sbf[(size_t)t0 * 42 + i];
  for (u32 i = tid; i < 336; i += 256) w_lds[i] = Wsbf[i];
  __syncthreads();
  float rv[42];
#pragma unroll
  for (int q = 0; q < 42; ++q) rv[q] = s_lds[tid * 42 + q];
  float o[8] = {0.f, 0.f, 0.f, 0.f, 0.f, 0.f, 0.f, 0.f};
#pragma unroll
  for (int q = 0; q < 42; ++q) {
    float r = rv[q];
#pragma unroll
    for (int c = 0; c < 8; ++c) o[c] += r * w_lds[q * 8 + c];
  }
  float* dst = sp + (size_t)(t0 + tid) * 8;
  f32x4 v0, v1;
#pragma unroll
  for (int j = 0; j < 4; ++j) { v0[j] = o[j]; v1[j] = o[4 + j]; }
  *(f32x4*)dst = v0;
  *(f32x4*)(dst + 4) = v1;
}

// ---------------------------------------------------------------------------
// S4: the big one.  Per block: 128 triplets.
//   X[t][h] = ek[kj[t]][h] (gathered, swizzled LDS)
//   acc[t][n] = sum_b sp[t][b] * (X @ WbilT[b])[t][n]   (f32)
//   atomic scatter: aggr[ji[t]][n] += acc[t][n]
__global__ __launch_bounds__(256) void k_bil(
    const int* __restrict__ trip, const char* __restrict__ ek,
    const float* __restrict__ sp, const char* __restrict__ WbilT, float* __restrict__ aggr) {
  extern __shared__ char lds[];
  char* ldsX = lds;                       // 32768
  char* ldsW = lds + 32768;               // 32768
  float* spT = (float*)(lds + 65536);     // [8][128]
  int* kjl = (int*)(lds + 69632);         // 128
  int* jil = (int*)(lds + 70144);         // 128
  const u32 tid = threadIdx.x, lane = tid & 63, wid = tid >> 6;
  const u32 t0 = blockIdx.x << 7;

  if (tid < 128) {
    kjl[tid] = trip[t0 + tid];
    jil[tid] = trip[T_N + t0 + tid];
  }
  {
    f32x4 v = *(const f32x4*)(sp + (size_t)t0 * 8 + tid * 4);
    u32 row = tid >> 1, c0 = (tid & 1) * 4;
#pragma unroll
    for (int j = 0; j < 4; ++j) spT[(c0 + j) * 128 + row] = v[j];
  }
  __syncthreads();
#pragma unroll
  for (int it = 0; it < 8; ++it) {   // gather X
    u32 q = tid + it * 256, row = q >> 4, c = q & 15;
    gld_lds16(ek + (size_t)kjl[row] * 256 + ((c ^ (row & 7)) << 4), ldsX + q * 16);
  }
#pragma unroll
  for (int it = 0; it < 8; ++it) {   // stage W for b=0
    u32 q = tid + it * 256, n = q >> 4, c = q & 15;
    gld_lds16(WbilT + n * 256 + ((c ^ (n & 7)) << 4), ldsW + q * 16);
  }
  __syncthreads();

  const u32 wm = wid >> 1, wn = wid & 1, rb = wm << 6, cb = wn << 6;
  f32x4 acc[4][4] = {};
  for (int b = 0; b < 8; ++b) {
    bf16x8 Bf[4][4];
#pragma unroll
    for (int ni = 0; ni < 4; ++ni) {
      u32 n = cb + ni * 16 + (lane & 15);
#pragma unroll
      for (int ks = 0; ks < 4; ++ks)
        Bf[ni][ks] = *(const bf16x8*)(ldsW + (n << 8) + ((((u32)(ks * 4) + (lane >> 4)) ^ (n & 7)) << 4));
    }
    __syncthreads();   // all waves captured Bf; ldsW is free for the next slice
    if (b < 7) {
      const char* wsrc = WbilT + (size_t)(b + 1) * 32768;
#pragma unroll
      for (int it = 0; it < 8; ++it) {
        u32 q = tid + it * 256, n = q >> 4, c = q & 15;
        gld_lds16(wsrc + n * 256 + ((c ^ (n & 7)) << 4), ldsW + q * 16);
      }
    }
#pragma unroll
    for (int mi = 0; mi < 4; ++mi) {
      u32 row = rb + mi * 16 + (lane & 15);
      bf16x8 Af[4];
#pragma unroll
      for (int ks = 0; ks < 4; ++ks)
        Af[ks] = *(const bf16x8*)(ldsX + (row << 8) + ((((u32)(ks * 4) + (lane >> 4)) ^ (row & 7)) << 4));
      f32x4 s4 = *(const f32x4*)(spT + b * 128 + rb + mi * 16 + ((lane >> 4) << 2));
#pragma unroll
      for (int ni = 0; ni < 4; ++ni) {
        f32x4 p = {0.f, 0.f, 0.f, 0.f};
#pragma unroll
        for (int ks = 0; ks < 4; ++ks) p = mfma16(Af[ks], Bf[ni][ks], p);
        acc[mi][ni] += s4 * p;
      }
    }
    __syncthreads();   // drains vmcnt: next slice's W staged before next Bf load
  }
  // scatter segment-sum
#pragma unroll
  for (int mi = 0; mi < 4; ++mi) {
    u32 rloc = rb + mi * 16 + ((lane >> 4) << 2);
#pragma unroll
    for (int j = 0; j < 4; ++j) {
      int e = jil[rloc + j];
      float* dst = aggr + (size_t)e * 128 + cb + (lane & 15);
#pragma unroll
      for (int ni = 0; ni < 4; ++ni) unsafeAtomicAdd(dst + ni * 16, acc[mi][ni][j]);
    }
  }
}

// ---------------------------------------------------------------------------
// Shared E-level GEMM: [128 rows] x WT[128][128].
//  tr:  0 = A from bf16 src (async copy);  1 = silu(bf16 src);  3 = silu(f32 src)
//  epi: 0 = silu(acc+bias);  1 = acc+bias (+E1 bf16)(+E2 f32);  2 = Madd_f32 + silu(acc+bias)
//  outf: 0 -> dstb bf16;  1 -> dstf f32
__global__ __launch_bounds__(256) void k_gemm128(
    const u16* __restrict__ Abf, const float* __restrict__ Af32, int tr,
    const char* __restrict__ WT, const float* __restrict__ bias,
    const u16* __restrict__ E1, const float* __restrict__ E2, const float* __restrict__ Madd,
    int epi, u16* __restrict__ dstb, float* __restrict__ dstf, int outf) {
  extern __shared__ char lds[];
  char* ldsA = lds;
  char* ldsB = lds + 32768;
  const u32 tid = threadIdx.x, lane = tid & 63, wid = tid >> 6;
  const u32 r0 = blockIdx.x << 7;

  if (tr == 0) {
    const char* src = (const char*)Abf + (size_t)r0 * 256;
#pragma unroll
    for (int it = 0; it < 8; ++it) {
      u32 q = tid + it * 256, row = q >> 4, c = q & 15;
      gld_lds16(src + row * 256 + ((c ^ (row & 7)) << 4), ldsA + q * 16);
    }
  } else {
    for (int it = 0; it < 8; ++it) {
      u32 q = tid + it * 256, row = q >> 4, c = q & 15;
      float f[8];
      if (tr == 3) {
        const float* s = Af32 + (size_t)(r0 + row) * 128 + c * 8;
        f32x4 a0 = *(const f32x4*)s, a1 = *(const f32x4*)(s + 4);
#pragma unroll
        for (int j = 0; j < 4; ++j) { f[j] = silu_f(a0[j]); f[4 + j] = silu_f(a1[j]); }
      } else {
        u32x4 v = *(const u32x4*)((const char*)Abf + (size_t)(r0 + row) * 256 + c * 16);
#pragma unroll
        for (int j = 0; j < 4; ++j) {
          f[2 * j] = silu_f(bf2f(v[j] & 0xffffu));
          f[2 * j + 1] = silu_f(bf2f(v[j] >> 16));
        }
      }
      u32x4 w;
#pragma unroll
      for (int j = 0; j < 4; ++j) w[j] = (u32)f2bf(f[2 * j]) | ((u32)f2bf(f[2 * j + 1]) << 16);
      *(u32x4*)(ldsA + (row << 8) + ((c ^ (row & 7)) << 4)) = w;
    }
  }
#pragma unroll
  for (int it = 0; it < 8; ++it) {
    u32 q = tid + it * 256, n = q >> 4, c = q & 15;
    gld_lds16(WT + n * 256 + ((c ^ (n & 7)) << 4), ldsB + q * 16);
  }
  __syncthreads();

  const u32 wm = wid >> 1, wn = wid & 1, rb = wm << 6, cb = wn << 6;
  f32x4 acc[4][4] = {};
  bf16x8 Bf[4][4];
#pragma unroll
  for (int ni = 0; ni < 4; ++ni) {
    u32 n = cb + ni * 16 + (lane & 15);
#pragma unroll
    for (int ks = 0; ks < 4; ++ks)
      Bf[ni][ks] = *(const bf16x8*)(ldsB + (n << 8) + ((((u32)(ks * 4) + (lane >> 4)) ^ (n & 7)) << 4));
  }
#pragma unroll
  for (int mi = 0; mi < 4; ++mi) {
    u32 row = rb + mi * 16 + (lane & 15);
    bf16x8 Af[4];
#pragma unroll
    for (int ks = 0; ks < 4; ++ks)
      Af[ks] = *(const bf16x8*)(ldsA + (row << 8) + ((((u32)(ks * 4) + (lane >> 4)) ^ (row & 7)) << 4));
#pragma unroll
    for (int ni = 0; ni < 4; ++ni)
#pragma unroll
      for (int ks = 0; ks < 4; ++ks) acc[mi][ni] = mfma16(Af[ks], Bf[ni][ks], acc[mi][ni]);
  }
#pragma unroll
  for (int mi = 0; mi < 4; ++mi) {
    u32 rloc = rb + mi * 16 + ((lane >> 4) << 2);
#pragma unroll
    for (int j = 0; j < 4; ++j) {
#pragma unroll
      for (int ni = 0; ni < 4; ++ni) {
        u32 col = cb + ni * 16 + (lane & 15);
        size_t gi = (size_t)(r0 + rloc + j) * 128 + col;
        float v = acc[mi][ni][j] + bias[col];
        float o;
        if (epi == 0) o = silu_f(v);
        else if (epi == 1) {
          o = v;
          if (E1) o += bf2f(E1[gi]);
          if (E2) o += E2[gi];
        } else o = Madd[gi] + silu_f(v);
        if (outf) dstf[gi] = o;
        else dstb[gi] = f2bf(o);
      }
    }
  }
}

// ---------------------------------------------------------------------------
extern "C" void kernel_launch(void* const* d_in, const int* in_sizes, int n_in,
                              void* d_out, int out_size, void* d_ws, size_t ws_size,
                              hipStream_t stream) {
  const float* m = (const float*)d_in[0];
  const float* rbf = (const float*)d_in[1];
  const float* sbf = (const float*)d_in[2];
  const int* trip = (const int*)d_in[4];
  const float* Wrbf = (const float*)d_in[5];
  const float* Wsbf = (const float*)d_in[6];
  const float* Wkj = (const float*)d_in[7];
  const float* bkj = (const float*)d_in[8];
  const float* Wji = (const float*)d_in[9];
  const float* bji = (const float*)d_in[10];
  const float* Wbil = (const float*)d_in[11];
  const float* r1w1 = (const float*)d_in[12];
  const float* r1b1 = (const float*)d_in[13];
  const float* r1w2 = (const float*)d_in[14];
  const float* r1b2 = (const float*)d_in[15];
  const float* r2w1 = (const float*)d_in[16];
  const float* r2b1 = (const float*)d_in[17];
  const float* r2w2 = (const float*)d_in[18];
  const float* r2b2 = (const float*)d_in[19];
  const float* Wout = (const float*)d_in[20];
  const float* bout = (const float*)d_in[21];

  char* ws = (char*)d_ws;
  char* W2T = ws;                          // 65536 B
  char* WbilT = ws + 65536;                // 262144 B
  char* rT = ws + 327680;                  // 5 * 32768 B
  u16* ek = (u16*)(ws + 524288);           // E*128 bf16
  float* sp = (float*)(ws + 34078720);     // T*8 f32
  float* aggr = (float*)(ws + 67633152);   // E*128 f32 (x_ji seeded, then scatter)
  u16* hbuf = (u16*)(ws + 134742016);      // E*128 bf16 (h1/h2/x3)
  u16* x2 = (u16*)(ws + 168296448);        // E*128 bf16
  // total ws use: 201850880 B

  hipFuncSetAttribute((const void*)k_pre, hipFuncAttributeMaxDynamicSharedMemorySize, 104448);
  hipFuncSetAttribute((const void*)k_sbf, hipFuncAttributeMaxDynamicSharedMemorySize, 44352);
  hipFuncSetAttribute((const void*)k_bil, hipFuncAttributeMaxDynamicSharedMemorySize, 70656);
  hipFuncSetAttribute((const void*)k_gemm128, hipFuncAttributeMaxDynamicSharedMemorySize, 65536);

  k_transpose<<<960, 256, 0, stream>>>(Wji, Wkj, Wbil, r1w1, r1w2, r2w1, r2w2, Wout, (u16*)ws);
  k_pre<<<1024, 512, 104448, stream>>>(m, rbf, Wrbf, bkj, bji, W2T, aggr, ek);
  k_sbf<<<4096, 256, 44352, stream>>>(sbf, Wsbf, sp);
  k_bil<<<8192, 256, 70656, stream>>>(trip, (const char*)ek, sp, WbilT, aggr);
  // residual block 1: h1 = silu(silu(m_new)@r1w1 + r1b1); x2 = m_new + h1@r1w2 + r1b2
  k_gemm128<<<1024, 256, 65536, stream>>>(nullptr, aggr, 3, rT, r1b1,
                                          nullptr, nullptr, nullptr, 0, hbuf, nullptr, 0);
  k_gemm128<<<1024, 256, 65536, stream>>>(hbuf, nullptr, 0, rT + 32768, r1b2,
                                          nullptr, aggr, nullptr, 1, x2, nullptr, 0);
  // residual block 2
  k_gemm128<<<1024, 256, 65536, stream>>>(x2, nullptr, 1, rT + 65536, r2b1,
                                          nullptr, nullptr, nullptr, 0, hbuf, nullptr, 0);
  k_gemm128<<<1024, 256, 65536, stream>>>(hbuf, nullptr, 0, rT + 98304, r2b2,
                                          x2, nullptr, nullptr, 1, hbuf, nullptr, 0);
  // output projection + final residual: out = m + silu(x3@Wout + bout)   (f32)
  k_gemm128<<<1024, 256, 65536, stream>>>(hbuf, nullptr, 0, rT + 131072, bout,
                                          nullptr, nullptr, m, 2, nullptr, (float*)d_out, 1);
}

// Round 3
// 854.047 us; speedup vs baseline: 1.1766x; 1.1766x over previous
//
#include <hip/hip_runtime.h>
#include <hip/hip_bf16.h>
#include <stdint.h>

typedef uint16_t u16;
typedef uint32_t u32;
typedef uint64_t u64;
typedef short bf16x8 __attribute__((ext_vector_type(8)));   // 8 bf16 in 4 VGPRs
typedef float f32x4 __attribute__((ext_vector_type(4)));
typedef u32 u32x4 __attribute__((ext_vector_type(4)));

#define E_N 131072
#define T_N 1048576

__device__ __forceinline__ float bf2f(u32 u) { return __builtin_bit_cast(float, u << 16); }
__device__ __forceinline__ u16 f2bf(float f) {
  u32 u = __builtin_bit_cast(u32, f);
  return (u16)((u + 0x7fffu + ((u >> 16) & 1u)) >> 16);   // RNE
}
__device__ __forceinline__ float silu_f(float x) { return x / (1.0f + __expf(-x)); }
__device__ __forceinline__ f32x4 mfma16(bf16x8 a, bf16x8 b, f32x4 c) {
  return __builtin_amdgcn_mfma_f32_16x16x32_bf16(a, b, c, 0, 0, 0);
}
// async global->LDS, 16B per lane. LDS dest is wave-uniform base + lane*16;
// swizzle is applied on the GLOBAL source address (rule #21).
__device__ __forceinline__ void gld_lds16(const void* g, void* l) {
  __builtin_amdgcn_global_load_lds((const __attribute__((address_space(1))) u32*)g,
                                   (__attribute__((address_space(3))) u32*)l, 16, 0, 0);
}

// ---------------------------------------------------------------------------
// T0: convert+transpose all f32 weight matrices into ws as [n][k] row-major bf16.
//  region 0: W2T[256][128]   (n<128: W_ji, n>=128: W_kj)       32768 elts
//  region 1: WbilT[8][128][128]                                131072 elts
//  region 2: {r1w1,r1w2,r2w1,r2w2,Wout}T each [128][128]       81920 elts
__global__ __launch_bounds__(256) void k_transpose(
    const float* __restrict__ Wji, const float* __restrict__ Wkj, const float* __restrict__ Wbil,
    const float* __restrict__ w11, const float* __restrict__ w12,
    const float* __restrict__ w21, const float* __restrict__ w22, const float* __restrict__ wout,
    u16* __restrict__ dst) {
  u32 idx = blockIdx.x * 256 + threadIdx.x;
  if (idx < 32768) {
    u32 n = idx >> 7, h = idx & 127;
    dst[idx] = f2bf((n < 128) ? Wji[h * 128 + n] : Wkj[h * 128 + (n - 128)]);
  } else if (idx < 32768 + 131072) {
    u32 q = idx - 32768;
    u32 b = q >> 14, n = (q >> 7) & 127, h = q & 127;
    dst[idx] = f2bf(Wbil[h * 1024 + b * 128 + n]);
  } else if (idx < 245760) {
    u32 q = idx - 163840;
    u32 r = q >> 14, n = (q >> 7) & 127, h = q & 127;
    const float* src = (r == 0) ? w11 : (r == 1) ? w12 : (r == 2) ? w21 : (r == 3) ? w22 : wout;
    dst[idx] = f2bf(src[h * 128 + n]);
  }
}

// ---------------------------------------------------------------------------
// S2: per-edge pre-GEMM.  [128 rows] x W2T[256][128].
//  cols   0..127 : aggr[row][col] = silu(m@W_ji + b_ji)   (f32, seeds segment sum)
//  cols 128..255 : ek[row][c2]    = silu(m@W_kj + b_kj) * (rbf@W_rbf)   (bf16)
__global__ __launch_bounds__(512) void k_pre(
    const float* __restrict__ m, const float* __restrict__ rbf, const float* __restrict__ Wrbf,
    const float* __restrict__ bkj, const float* __restrict__ bji,
    const char* __restrict__ W2T, float* __restrict__ aggr, u16* __restrict__ ek) {
  extern __shared__ char lds[];
  char* ldsA = lds;                              // 32768: m tile [128][128] bf16 (swz)
  char* ldsB = lds + 32768;                      // 65536: W2T [256][128] bf16 (swz)
  float* ldsRbf = (float*)(lds + 98304);         // [128][6]
  float* ldsWr = (float*)(lds + 101376);         // [6][128]
  const u32 tid = threadIdx.x, lane = tid & 63;
  const u32 r0 = blockIdx.x << 7;

  // stage m (f32) -> bf16 swizzled LDS, reg-staged
#pragma unroll
  for (int it = 0; it < 8; ++it) {
    u32 q = tid + it * 512;          // [0,4096): 128 rows x 32 groups of 4 elems
    u32 row = q >> 5, c4 = q & 31;
    f32x4 v = *(const f32x4*)(m + (size_t)(r0 + row) * 128 + c4 * 4);
    u32 c = c4 >> 1, half = c4 & 1;
    u32 w0 = (u32)f2bf(v[0]) | ((u32)f2bf(v[1]) << 16);
    u32 w1 = (u32)f2bf(v[2]) | ((u32)f2bf(v[3]) << 16);
    u32 ofs = (row << 8) + ((c ^ (row & 7)) << 4) + half * 8;
    *(u64*)(ldsA + ofs) = (u64)w0 | ((u64)w1 << 32);
  }
#pragma unroll
  for (int it = 0; it < 8; ++it) {   // W2T bf16 via async copy
    u32 q = tid + it * 512, n = q >> 4, c = q & 15;
    gld_lds16(W2T + n * 256 + ((c ^ (n & 7)) << 4), ldsB + q * 16);
  }
  for (u32 i = tid; i < 768; i += 512) ldsRbf[i] = rbf[(size_t)r0 * 6 + i];
  for (u32 i = tid; i < 768; i += 512) ldsWr[i] = Wrbf[i];
  __syncthreads();

  const u32 wid = tid >> 6, wm = wid >> 2, wn = wid & 3;
  const u32 rb = wm << 6, cb = wn << 6;
  f32x4 acc[4][4] = {};
  bf16x8 Bf[4][4];
#pragma unroll
  for (int ni = 0; ni < 4; ++ni) {
    u32 n = cb + ni * 16 + (lane & 15);
#pragma unroll
    for (int ks = 0; ks < 4; ++ks)
      Bf[ni][ks] = *(const bf16x8*)(ldsB + (n << 8) + ((((u32)(ks * 4) + (lane >> 4)) ^ (n & 7)) << 4));
  }
#pragma unroll
  for (int mi = 0; mi < 4; ++mi) {
    u32 row = rb + mi * 16 + (lane & 15);
    bf16x8 Af[4];
#pragma unroll
    for (int ks = 0; ks < 4; ++ks)
      Af[ks] = *(const bf16x8*)(ldsA + (row << 8) + ((((u32)(ks * 4) + (lane >> 4)) ^ (row & 7)) << 4));
#pragma unroll
    for (int ni = 0; ni < 4; ++ni)
#pragma unroll
      for (int ks = 0; ks < 4; ++ks) acc[mi][ni] = mfma16(Af[ks], Bf[ni][ks], acc[mi][ni]);
  }
  // epilogue
#pragma unroll
  for (int mi = 0; mi < 4; ++mi) {
    u32 rloc = rb + mi * 16 + ((lane >> 4) << 2);
#pragma unroll
    for (int j = 0; j < 4; ++j) {
      u32 rl = rloc + j;
      size_t grow = r0 + rl;
#pragma unroll
      for (int ni = 0; ni < 4; ++ni) {
        u32 col = cb + ni * 16 + (lane & 15);
        float v = acc[mi][ni][j];
        if (col < 128) {
          aggr[grow * 128 + col] = silu_f(v + bji[col]);
        } else {
          u32 c2 = col - 128;
          float rw = 0.f;
#pragma unroll
          for (int q = 0; q < 6; ++q) rw += ldsRbf[rl * 6 + q] * ldsWr[q * 128 + c2];
          ek[grow * 128 + c2] = f2bf(silu_f(v + bkj[c2]) * rw);
        }
      }
    }
  }
}

// ---------------------------------------------------------------------------
// S4: per block 128 triplets.
//   sp[t][b]  = sbf[t] @ Wsbf            (computed in-block, spT LDS)
//   X[t][h]   = ek[kj[t]][h]             (gathered -> registers, held all slices)
//   acc[t][n] = sum_b sp[t][b] * (X @ WbilT[b])[t][n]
//   atomic scatter: aggr[ji[t]][n] += acc[t][n]
__global__ __launch_bounds__(256, 2) void k_bil(
    const int* __restrict__ trip, const char* __restrict__ ek,
    const float* __restrict__ sbf, const float* __restrict__ Wsbf,
    const char* __restrict__ WbilT, float* __restrict__ aggr) {
  extern __shared__ char lds[];
  char* buf0 = lds;                       // 32768: sbf stage, then W slices even
  char* buf1 = lds + 32768;               // 32768: X gather, then W slices odd
  float* spT = (float*)(lds + 65536);     // [8][128]
  int* kjl = (int*)(lds + 69632);         // 128
  int* jil = (int*)(lds + 70144);         // 128
  float* wsb = (float*)(lds + 70656);     // [42][8]
  const u32 tid = threadIdx.x, lane = tid & 63, wid = tid >> 6;
  const u32 t0 = blockIdx.x << 7;
  const u32 wm = wid >> 1, wn = wid & 1, rb = wm << 6, cb = wn << 6;

  // phase A: indices + sbf tile + Wsbf
  if (tid < 128) {
    kjl[tid] = trip[t0 + tid];
    jil[tid] = trip[T_N + t0 + tid];
  }
  {
    const f32x4* src = (const f32x4*)(sbf + (size_t)t0 * 42);
    f32x4* dst = (f32x4*)buf0;
    for (u32 i = tid; i < 1344; i += 256) dst[i] = src[i];        // 128*42 f32
    const f32x4* ws4 = (const f32x4*)Wsbf;
    for (u32 i = tid; i < 84; i += 256) ((f32x4*)wsb)[i] = ws4[i]; // 336 f32
  }
  __syncthreads();

  // phase B: sp = sbf @ Wsbf -> spT ;  X gather -> buf1
  {
    const float* sbfl = (const float*)buf0;
    u32 row = tid >> 1, c4 = (tid & 1) * 4;
    float o0 = 0.f, o1 = 0.f, o2 = 0.f, o3 = 0.f;
#pragma unroll
    for (int q = 0; q < 42; ++q) {
      float r = sbfl[row * 42 + q];
      const float* w = wsb + q * 8 + c4;
      o0 += r * w[0]; o1 += r * w[1]; o2 += r * w[2]; o3 += r * w[3];
    }
    spT[(c4 + 0) * 128 + row] = o0;
    spT[(c4 + 1) * 128 + row] = o1;
    spT[(c4 + 2) * 128 + row] = o2;
    spT[(c4 + 3) * 128 + row] = o3;
  }
#pragma unroll
  for (int it = 0; it < 8; ++it) {   // gather X into buf1
    u32 q = tid + it * 256, row = q >> 4, c = q & 15;
    gld_lds16(ek + (size_t)kjl[row] * 256 + ((c ^ (row & 7)) << 4), buf1 + q * 16);
  }
  __syncthreads();

  // phase C: stage W0 -> buf0 (sbf dead); hoist X fragments to registers
#pragma unroll
  for (int it = 0; it < 8; ++it) {
    u32 q = tid + it * 256, n = q >> 4, c = q & 15;
    gld_lds16(WbilT + n * 256 + ((c ^ (n & 7)) << 4), buf0 + q * 16);
  }
  bf16x8 Afr[4][4];
#pragma unroll
  for (int mi = 0; mi < 4; ++mi) {
    u32 row = rb + mi * 16 + (lane & 15);
#pragma unroll
    for (int ks = 0; ks < 4; ++ks)
      Afr[mi][ks] = *(const bf16x8*)(buf1 + (row << 8) + ((((u32)(ks * 4) + (lane >> 4)) ^ (row & 7)) << 4));
  }
  __syncthreads();

  // phase D: 8 b-slices, W double-buffered
  f32x4 acc[4][4] = {};
  for (int b = 0; b < 8; ++b) {
    char* cur = (b & 1) ? buf1 : buf0;
    if (b < 7) {
      char* nxt = (b & 1) ? buf0 : buf1;
      const char* wsrc = WbilT + (size_t)(b + 1) * 32768;
#pragma unroll
      for (int it = 0; it < 8; ++it) {
        u32 q = tid + it * 256, n = q >> 4, c = q & 15;
        gld_lds16(wsrc + n * 256 + ((c ^ (n & 7)) << 4), nxt + q * 16);
      }
    }
    bf16x8 Bf[4][4];
#pragma unroll
    for (int ni = 0; ni < 4; ++ni) {
      u32 n = cb + ni * 16 + (lane & 15);
#pragma unroll
      for (int ks = 0; ks < 4; ++ks)
        Bf[ni][ks] = *(const bf16x8*)(cur + (n << 8) + ((((u32)(ks * 4) + (lane >> 4)) ^ (n & 7)) << 4));
    }
#pragma unroll
    for (int mi = 0; mi < 4; ++mi) {
      f32x4 s4 = *(const f32x4*)(spT + b * 128 + rb + mi * 16 + ((lane >> 4) << 2));
#pragma unroll
      for (int ni = 0; ni < 4; ++ni) {
        f32x4 p = {0.f, 0.f, 0.f, 0.f};
#pragma unroll
        for (int ks = 0; ks < 4; ++ks) p = mfma16(Afr[mi][ks], Bf[ni][ks], p);
        acc[mi][ni] += s4 * p;
      }
    }
    __syncthreads();   // waves done with cur; staging of nxt drained
  }

  // scatter segment-sum
#pragma unroll
  for (int mi = 0; mi < 4; ++mi) {
    u32 rloc = rb + mi * 16 + ((lane >> 4) << 2);
#pragma unroll
    for (int j = 0; j < 4; ++j) {
      int e = jil[rloc + j];
      float* dst = aggr + (size_t)e * 128 + cb + (lane & 15);
#pragma unroll
      for (int ni = 0; ni < 4; ++ni) unsafeAtomicAdd(dst + ni * 16, acc[mi][ni][j]);
    }
  }
}

// ---------------------------------------------------------------------------
// S5: fused residual chain.  Per block 128 rows, 5 back-to-back 128^3 GEMMs.
//   x  = m_new (aggr);        h1 = silu(silu(x)@W1+b1);   x2 = x + h1@W2+b2
//   h2 = silu(silu(x2)@W3+b3); x3 = x2 + h2@W4+b4;        out = m + silu(x3@W5+b5)
__global__ __launch_bounds__(256, 2) void k_res(
    const float* __restrict__ aggr, const float* __restrict__ m,
    const char* __restrict__ rT,
    const float* __restrict__ rb1, const float* __restrict__ rb2,
    const float* __restrict__ rb3, const float* __restrict__ rb4,
    const float* __restrict__ bo, float* __restrict__ out) {
  extern __shared__ char lds[];
  char* ldsA = lds;
  char* ldsB = lds + 32768;
  const u32 tid = threadIdx.x, lane = tid & 63, wid = tid >> 6;
  const u32 r0 = blockIdx.x << 7;
  const u32 wm = wid >> 1, wn = wid & 1, rbw = wm << 6, cbw = wn << 6;
  const u32 lrow = (lane >> 4) << 2, lcol = lane & 15;

  auto stageB = [&](const char* WT) {
#pragma unroll
    for (int it = 0; it < 8; ++it) {
      u32 q = tid + it * 256, n = q >> 4, c = q & 15;
      gld_lds16(WT + n * 256 + ((c ^ (n & 7)) << 4), ldsB + q * 16);
    }
  };
  auto writeA = [&](u32 row, u32 col, float v) {
    *(u16*)(ldsA + (row << 8) + ((((col >> 3)) ^ (row & 7)) << 4) + (col & 7) * 2) = f2bf(v);
  };
  auto compute = [&](f32x4 (&acc)[4][4]) {
#pragma unroll
    for (int mi = 0; mi < 4; ++mi) {
      u32 row = rbw + mi * 16 + lcol;
      bf16x8 Af[4];
#pragma unroll
      for (int ks = 0; ks < 4; ++ks)
        Af[ks] = *(const bf16x8*)(ldsA + (row << 8) + ((((u32)(ks * 4) + (lane >> 4)) ^ (row & 7)) << 4));
#pragma unroll
      for (int ni = 0; ni < 4; ++ni) {
        u32 n = cbw + ni * 16 + lcol;
#pragma unroll
        for (int ks = 0; ks < 4; ++ks) {
          bf16x8 Bk = *(const bf16x8*)(ldsB + (n << 8) + ((((u32)(ks * 4) + (lane >> 4)) ^ (n & 7)) << 4));
          acc[mi][ni] = mfma16(Af[ks], Bk, acc[mi][ni]);
        }
      }
    }
  };
  auto zero = [&](f32x4 (&acc)[4][4]) {
#pragma unroll
    for (int a = 0; a < 4; ++a)
#pragma unroll
      for (int c = 0; c < 4; ++c) acc[a][c] = (f32x4){0.f, 0.f, 0.f, 0.f};
  };

  // phase 0: load x at acc positions; stage W1; write silu(x) -> ldsA
  f32x4 xr[4][4];
#pragma unroll
  for (int mi = 0; mi < 4; ++mi)
#pragma unroll
    for (int j = 0; j < 4; ++j) {
      const float* src = aggr + (size_t)(r0 + rbw + mi * 16 + lrow + j) * 128 + cbw + lcol;
#pragma unroll
      for (int ni = 0; ni < 4; ++ni) xr[mi][ni][j] = src[ni * 16];
    }
  stageB(rT);
#pragma unroll
  for (int mi = 0; mi < 4; ++mi)
#pragma unroll
    for (int j = 0; j < 4; ++j) {
      u32 row = rbw + mi * 16 + lrow + j;
#pragma unroll
      for (int ni = 0; ni < 4; ++ni) writeA(row, cbw + ni * 16 + lcol, silu_f(xr[mi][ni][j]));
    }
  __syncthreads();

  f32x4 acc[4][4];
  // GEMM1: h1 = silu(. + b1)
  zero(acc); compute(acc);
  __syncthreads();
#pragma unroll
  for (int mi = 0; mi < 4; ++mi)
#pragma unroll
    for (int j = 0; j < 4; ++j) {
      u32 row = rbw + mi * 16 + lrow + j;
#pragma unroll
      for (int ni = 0; ni < 4; ++ni) {
        u32 col = cbw + ni * 16 + lcol;
        writeA(row, col, silu_f(acc[mi][ni][j] + rb1[col]));
      }
    }
  stageB(rT + 32768);
  __syncthreads();

  // GEMM2: x2 = x + . + b2 ; A3 = silu(x2)
  zero(acc); compute(acc);
  __syncthreads();
#pragma unroll
  for (int mi = 0; mi < 4; ++mi)
#pragma unroll
    for (int j = 0; j < 4; ++j) {
      u32 row = rbw + mi * 16 + lrow + j;
#pragma unroll
      for (int ni = 0; ni < 4; ++ni) {
        u32 col = cbw + ni * 16 + lcol;
        xr[mi][ni][j] += acc[mi][ni][j] + rb2[col];
        writeA(row, col, silu_f(xr[mi][ni][j]));
      }
    }
  stageB(rT + 65536);
  __syncthreads();

  // GEMM3: h2 = silu(. + b3)
  zero(acc); compute(acc);
  __syncthreads();
#pragma unroll
  for (int mi = 0; mi < 4; ++mi)
#pragma unroll
    for (int j = 0; j < 4; ++j) {
      u32 row = rbw + mi * 16 + lrow + j;
#pragma unroll
      for (int ni = 0; ni < 4; ++ni) {
        u32 col = cbw + ni * 16 + lcol;
        writeA(row, col, silu_f(acc[mi][ni][j] + rb3[col]));
      }
    }
  stageB(rT + 98304);
  __syncthreads();

  // GEMM4: x3 = x2 + . + b4 ; A5 = x3 (plain)
  zero(acc); compute(acc);
  __syncthreads();
#pragma unroll
  for (int mi = 0; mi < 4; ++mi)
#pragma unroll
    for (int j = 0; j < 4; ++j) {
      u32 row = rbw + mi * 16 + lrow + j;
#pragma unroll
      for (int ni = 0; ni < 4; ++ni) {
        u32 col = cbw + ni * 16 + lcol;
        xr[mi][ni][j] += acc[mi][ni][j] + rb4[col];
        writeA(row, col, xr[mi][ni][j]);
      }
    }
  stageB(rT + 131072);
  // xr dead (x3 now in ldsA) -> prefetch m tile into xr for the final residual
#pragma unroll
  for (int mi = 0; mi < 4; ++mi)
#pragma unroll
    for (int j = 0; j < 4; ++j) {
      const float* src = m + (size_t)(r0 + rbw + mi * 16 + lrow + j) * 128 + cbw + lcol;
#pragma unroll
      for (int ni = 0; ni < 4; ++ni) xr[mi][ni][j] = src[ni * 16];
    }
  __syncthreads();

  // GEMM5: out = m + silu(. + bo)
  zero(acc); compute(acc);
#pragma unroll
  for (int mi = 0; mi < 4; ++mi)
#pragma unroll
    for (int j = 0; j < 4; ++j) {
      size_t grow = r0 + rbw + mi * 16 + lrow + j;
#pragma unroll
      for (int ni = 0; ni < 4; ++ni) {
        u32 col = cbw + ni * 16 + lcol;
        out[grow * 128 + col] = xr[mi][ni][j] + silu_f(acc[mi][ni][j] + bo[col]);
      }
    }
}

// ---------------------------------------------------------------------------
extern "C" void kernel_launch(void* const* d_in, const int* in_sizes, int n_in,
                              void* d_out, int out_size, void* d_ws, size_t ws_size,
                              hipStream_t stream) {
  const float* m = (const float*)d_in[0];
  const float* rbf = (const float*)d_in[1];
  const float* sbf = (const float*)d_in[2];
  const int* trip = (const int*)d_in[4];
  const float* Wrbf = (const float*)d_in[5];
  const float* Wsbf = (const float*)d_in[6];
  const float* bkj = (const float*)d_in[8];
  const float* bji = (const float*)d_in[10];
  const float* r1b1 = (const float*)d_in[13];
  const float* r1b2 = (const float*)d_in[15];
  const float* r2b1 = (const float*)d_in[17];
  const float* r2b2 = (const float*)d_in[19];
  const float* bout = (const float*)d_in[21];

  char* ws = (char*)d_ws;
  char* W2T = ws;                          // 65536 B
  char* WbilT = ws + 65536;                // 262144 B
  char* rT = ws + 327680;                  // 5 * 32768 B
  u16* ek = (u16*)(ws + 524288);           // E*128 bf16
  float* aggr = (float*)(ws + 67633152);   // E*128 f32 (x_ji seeded, then scatter)

  hipFuncSetAttribute((const void*)k_pre, hipFuncAttributeMaxDynamicSharedMemorySize, 104448);
  hipFuncSetAttribute((const void*)k_bil, hipFuncAttributeMaxDynamicSharedMemorySize, 72000);
  hipFuncSetAttribute((const void*)k_res, hipFuncAttributeMaxDynamicSharedMemorySize, 65536);

  k_transpose<<<960, 256, 0, stream>>>(
      (const float*)d_in[9], (const float*)d_in[7], (const float*)d_in[11],
      (const float*)d_in[12], (const float*)d_in[14], (const float*)d_in[16],
      (const float*)d_in[18], (const float*)d_in[20], (u16*)ws);
  k_pre<<<1024, 512, 104448, stream>>>(m, rbf, Wrbf, bkj, bji, W2T, aggr, ek);
  k_bil<<<8192, 256, 72000, stream>>>(trip, (const char*)ek, sbf, Wsbf, WbilT, aggr);
  k_res<<<1024, 256, 65536, stream>>>(aggr, m, rT, r1b1, r1b2, r2b1, r2b2, bout,
                                      (float*)d_out);
}